// Round 10
// baseline (343.378 us; speedup 1.0000x reference)
//
#include <hip/hip_runtime.h>
#include <math.h>

#define NB   4
#define NBOX 512
#define CI   128
#define HH   376
#define WW   376
#define OC   28
#define HW   (HH * WW)   // 141376
// byte offset of zbuf (zeroed 256B) relative to featp base within d_ws:
// zbuf @ 208,409,600  -  featp @ 63,336,448
#define ZOFF 145073152u

typedef short short8  __attribute__((ext_vector_type(8)));
typedef __bf16 bf16x8 __attribute__((ext_vector_type(8)));
typedef float f32x16  __attribute__((ext_vector_type(16)));
typedef unsigned uint4v __attribute__((ext_vector_type(4)));

typedef const __attribute__((address_space(1))) void gas_void;
typedef __attribute__((address_space(3))) void las_void;

__device__ inline unsigned short f2bf(float f) {
    unsigned u = __builtin_bit_cast(unsigned, f);
    u = u + 0x7fffu + ((u >> 16) & 1u);   // RNE
    return (unsigned short)(u >> 16);
}

__device__ inline unsigned cvtpk_bf16(float lo, float hi) {
    unsigned r;
    asm("v_cvt_pk_bf16_f32 %0, %1, %2" : "=v"(r) : "v"(lo), "v"(hi));
    return r;
}

__device__ inline f32x16 mfma32(short8 a, short8 b, f32x16 c) {
    return __builtin_amdgcn_mfma_f32_32x32x16_bf16(
        __builtin_bit_cast(bf16x8, a), __builtin_bit_cast(bf16x8, b), c, 0, 0, 0);
}

// ================= prep: weights / BN / zero-slot =================
// w1p layout: [chunk=8][co=128][tap=9][slot s'][8 ci], s' = s ^ ((co>>2)&1)
__global__ void __launch_bounds__(256)
prep_kernel(const float* __restrict__ w1, const float* __restrict__ gamma,
            const float* __restrict__ beta, const float* __restrict__ rmean,
            const float* __restrict__ rvar, const float* __restrict__ w2,
            unsigned short* __restrict__ w1p, unsigned short* __restrict__ w2pB,
            float* __restrict__ bnsc, float* __restrict__ bnsh,
            unsigned short* __restrict__ zbuf)
{
    int idx = blockIdx.x * 256 + threadIdx.x;
    if (idx < 8 * 128 * 9 * 16) {          // 147456
        int e    = idx & 7;
        int sp   = (idx >> 3) & 1;
        int t9   = idx >> 4;               // chunk*1152 + co*9 + tap
        int tap  = t9 % 9;
        int t2   = t9 / 9;                 // chunk*128 + co
        int co   = t2 & 127;
        int chnk = t2 >> 7;
        int s    = sp ^ ((co >> 2) & 1);
        int ci   = chnk * 16 + s * 8 + e;
        w1p[idx] = f2bf(w1[((size_t)co * CI + ci) * 9 + tap]);
    }
    if (idx < 32 * 128) {                  // w2pB [32 o][128 co]
        int o = idx >> 7, k = idx & 127;
        w2pB[idx] = (o < OC) ? f2bf(w2[o * CI + k]) : (unsigned short)0;
    }
    if (idx < CI) {
        float rs = rsqrtf(rvar[idx] + 1e-3f);
        bnsc[idx] = gamma[idx] * rs;
        bnsh[idx] = beta[idx] - rmean[idx] * gamma[idx] * rs;
    }
    if (idx < 128) zbuf[idx] = 0;
}

// ================= prepass: feat [b][ci][y][x] f32 -> featp [b][y][x][128] bf16 =================
__global__ void __launch_bounds__(256)
prepass_kernel(const float* __restrict__ feat, unsigned short* __restrict__ featp)
{
    __shared__ unsigned short xl[64 * 136];
    const int t  = threadIdx.x;
    const int bb = blockIdx.x;                 // 4 * 2209
    const int b  = bb / 2209;
    const int s0 = (bb - b * 2209) * 64;

    const int pxq = t & 15;
    const int cib = t >> 4;
#pragma unroll
    for (int it = 0; it < 8; ++it) {
        int ci = it * 16 + cib;
        float4 v = *(const float4*)(feat + ((size_t)(b * CI + ci)) * HW + s0 + pxq * 4);
#pragma unroll
        for (int j = 0; j < 4; ++j)
            xl[(pxq * 4 + j) * 136 + ci] = f2bf((&v.x)[j]);
    }
    __syncthreads();
#pragma unroll
    for (int it = 0; it < 4; ++it) {
        int n  = it * 256 + t;                 // 0..1023
        int px = n >> 4, cs = n & 15;
        short8 v = *(const short8*)(xl + px * 136 + cs * 8);
        *(short8*)(featp + ((size_t)b * HW + s0 + px) * 128 + cs * 8) = v;
    }
}

// ================= fused conv: 3x3 MFMA + BN + ReLU + 1x1 MFMA =================
// block = 256 thr (4 waves), tile 16x16 px x 128 co. Wave w: local rows [4w,4w+4).
// 32x32x16 MFMA, swapped operands: A=weights(rows=co, LDS), B=feat(cols=px, GLOBAL).
// Feat B-frags via PLAIN C short8 loads (r9 lesson: inline-asm async loads let RA
// copy the dest regs before data lands). Compiler schedules/waitcnts them; the
// per-chunk 10KB feat window is L1-resident across the 9 taps.
// LDS holds WEIGHTS ONLY (36,864 B, single-buffered, two syncthreads per chunk).
// OOB px offsets point at a zeroed 256B region (ZOFF).
__global__ void __launch_bounds__(256, 2)
conv_mfma(const unsigned short* __restrict__ featp,
          const unsigned short* __restrict__ w1p,
          const float* __restrict__ bnsc, const float* __restrict__ bnsh,
          const unsigned short* __restrict__ w2pB,
          float* __restrict__ confi)
{
    __shared__ unsigned short wl[18432];   // weights only: 36,864 B

    const int tid  = threadIdx.x;
    const int w    = tid >> 6;             // 0..3
    const int lane = tid & 63;
    const int l31  = lane & 31;
    const int h    = lane >> 5;
    const int x0   = blockIdx.x * 16;
    const int y0   = blockIdx.y * 16;
    const int b    = blockIdx.z;
    const char* fpB = (const char*)featp;

    // ---- per-(pf,tap) 32-bit byte offsets into featp; OOB -> ZOFF (zeros) ----
    unsigned off0[9], off1[9];
    {
        const int lc = l31 & 15;
#pragma unroll
        for (int tap = 0; tap < 9; ++tap) {
            const int dy = tap / 3, dx = tap - 3 * (tap / 3);
#pragma unroll
            for (int pf = 0; pf < 2; ++pf) {
                int lr = w * 4 + pf * 2 + (l31 >> 4);
                int gy = y0 + lr + dy - 1;
                int gx = x0 + lc + dx - 1;
                bool ok = ((unsigned)gy < HH) && ((unsigned)gx < WW);
                unsigned o = ok
                    ? (unsigned)(((size_t)b * HW + (size_t)gy * WW + gx) * 256 + h * 16)
                    : (ZOFF + (unsigned)(h * 16));
                if (pf == 0) off0[tap] = o; else off1[tap] = o;
            }
        }
    }

    // ---- weight read bases (LDS) ----
    const int sw   = h ^ ((l31 >> 2) & 1);
    const int slA0 = (0 * 32 + l31) * 18 + sw;
    const int slA1 = (1 * 32 + l31) * 18 + sw;
    const int slA2 = (2 * 32 + l31) * 18 + sw;
    const int slA3 = (3 * 32 + l31) * 18 + sw;

    f32x16 acc[4][2];
#pragma unroll
    for (int nf = 0; nf < 4; ++nf)
#pragma unroll
        for (int pf = 0; pf < 2; ++pf)
#pragma unroll
            for (int e = 0; e < 16; ++e) acc[nf][pf][e] = 0.f;

    for (int chunk = 0; chunk < 8; ++chunk) {
        __syncthreads();   // previous chunk's wl readers done
        // stage weights chunk: 9 issues/wave x 64 lanes x 16B = 36,864 B total
#pragma unroll
        for (int j = 0; j < 9; ++j) {
            int i = w * 9 + j;
            __builtin_amdgcn_global_load_lds(
                (gas_void*)(w1p + (size_t)chunk * 18432 + (i * 64 + lane) * 8),
                (las_void*)(wl + i * 512), 16, 0, 0);
        }
        __syncthreads();   // stages landed (implicit vmcnt/lgkm drain)

#pragma unroll
        for (int tap = 0; tap < 9; ++tap) {
            short8 b0 = *(const short8*)(fpB + off0[tap]);
            short8 b1 = *(const short8*)(fpB + off1[tap]);
            short8 a0 = *(const short8*)(wl + slA0 * 8 + tap * 16);
            short8 a1 = *(const short8*)(wl + slA1 * 8 + tap * 16);
            short8 a2 = *(const short8*)(wl + slA2 * 8 + tap * 16);
            short8 a3 = *(const short8*)(wl + slA3 * 8 + tap * 16);
            acc[0][0] = mfma32(a0, b0, acc[0][0]);
            acc[0][1] = mfma32(a0, b1, acc[0][1]);
            acc[1][0] = mfma32(a1, b0, acc[1][0]);
            acc[1][1] = mfma32(a1, b1, acc[1][1]);
            acc[2][0] = mfma32(a2, b0, acc[2][0]);
            acc[2][1] = mfma32(a2, b1, acc[2][1]);
            acc[3][0] = mfma32(a3, b0, acc[3][0]);
            acc[3][1] = mfma32(a3, b1, acc[3][1]);
        }

        // advance offsets to next 16-ci chunk (+32 B)
#pragma unroll
        for (int t2 = 0; t2 < 9; ++t2) { off0[t2] += 32; off1[t2] += 32; }
    }

    // ---- BN + ReLU (co = 32nf + (reg&3) + 8q + 4h) ----
#pragma unroll
    for (int nf = 0; nf < 4; ++nf)
#pragma unroll
        for (int q = 0; q < 4; ++q) {
            float4 s4 = *(const float4*)(bnsc + nf * 32 + q * 8 + 4 * h);
            float4 t4 = *(const float4*)(bnsh + nf * 32 + q * 8 + 4 * h);
#pragma unroll
            for (int r = 0; r < 4; ++r)
#pragma unroll
                for (int pf = 0; pf < 2; ++pf)
                    acc[nf][pf][q * 4 + r] =
                        fmaxf(acc[nf][pf][q * 4 + r] * (&s4.x)[r] + (&t4.x)[r], 0.f);
        }

    // ---- 1x1 conv fully in-register: pack acc -> bf16 A-frags (cvt_pk + half-swap) ----
#pragma unroll
    for (int pf = 0; pf < 2; ++pf) {
        f32x16 o2;
#pragma unroll
        for (int e = 0; e < 16; ++e) o2[e] = 0.f;
#pragma unroll
        for (int nf = 0; nf < 4; ++nf) {
#pragma unroll
            for (int half = 0; half < 2; ++half) {
                const int qa = half * 2, qb = half * 2 + 1;
                unsigned A0 = cvtpk_bf16(acc[nf][pf][qa * 4 + 0], acc[nf][pf][qa * 4 + 1]);
                unsigned A1 = cvtpk_bf16(acc[nf][pf][qa * 4 + 2], acc[nf][pf][qa * 4 + 3]);
                unsigned B0 = cvtpk_bf16(acc[nf][pf][qb * 4 + 0], acc[nf][pf][qb * 4 + 1]);
                unsigned B1 = cvtpk_bf16(acc[nf][pf][qb * 4 + 2], acc[nf][pf][qb * 4 + 3]);
                unsigned sA0 = (unsigned)__shfl_xor((int)A0, 32);
                unsigned sA1 = (unsigned)__shfl_xor((int)A1, 32);
                unsigned sB0 = (unsigned)__shfl_xor((int)B0, 32);
                unsigned sB1 = (unsigned)__shfl_xor((int)B1, 32);
                uint4v uv;
                uv[0] = h ? sB0 : A0;      // k = 8h+0,1
                uv[1] = h ? sB1 : A1;      // k = 8h+2,3
                uv[2] = h ? B0  : sA0;     // k = 8h+4,5
                uv[3] = h ? B1  : sA1;     // k = 8h+6,7
                short8 a2 = __builtin_bit_cast(short8, uv);
                int ks = nf * 2 + half;
                short8 wfv = *(const short8*)(w2pB + l31 * 128 + ks * 16 + h * 8);
                o2 = mfma32(a2, wfv, o2);
            }
        }
        // store: lane holds o = l31, px per-reg
#pragma unroll
        for (int reg = 0; reg < 16; ++reg) {
            int row = (reg & 3) + 8 * (reg >> 2) + 4 * h;
            int pxl = w * 64 + pf * 32 + row;
            int y = y0 + (pxl >> 4), x = x0 + (pxl & 15);
            if (l31 < OC && x < WW && y < HH)
                confi[(((size_t)b * HH + y) * WW + x) * OC + l31] = o2[reg];
        }
    }
}

// ================= rotated-grid bilinear sampling + mean + sigmoid =================
__global__ void __launch_bounds__(256)
sample_kernel(const float* __restrict__ confi, const float* __restrict__ boxes,
              float* __restrict__ out)
{
    const int tid = threadIdx.x;
    const int lb  = tid >> 5;
    const int k   = tid & 31;
    const int box = blockIdx.x * 8 + lb;
    const int b   = box >> 9;
    const int n   = box & 511;

    const float* b5 = boxes + ((size_t)b * NBOX + n) * 5;
    float xg = b5[0], yg = b5[1], wg = b5[2], lg = b5[3], rg = b5[4];
    float cr = cosf(rg), sr = sinf(rg);

    float samp = 0.f;
    if (k < OC) {
        int i = k / 7, j = k - 7 * i;
        float xx = (-0.5f + (float)i * (1.0f / 3.0f)) * wg;
        float yy = (-0.5f + (float)j * (1.0f / 6.0f)) * lg;
        float px = xx * cr + yy * sr + xg;
        float py = yy * cr - xx * sr + yg;
        float fx = px * ((float)WW / (float)(WW - 1)) - 0.5f;
        float fy = py * ((float)HH / (float)(HH - 1)) - 0.5f;
        float x0f = floorf(fx), y0f = floorf(fy);
        float wx = fx - x0f, wy = fy - y0f;
        int xi = (int)x0f, yi = (int)y0f;

        float v00 = 0.f, v10 = 0.f, v01 = 0.f, v11 = 0.f;
        bool okx0 = (xi >= 0)     && (xi <= WW - 1);
        bool okx1 = (xi + 1 >= 0) && (xi + 1 <= WW - 1);
        bool oky0 = (yi >= 0)     && (yi <= HH - 1);
        bool oky1 = (yi + 1 >= 0) && (yi + 1 <= HH - 1);
        if (okx0 && oky0) v00 = confi[(((size_t)b * HH + yi)     * WW + xi)     * OC + k];
        if (okx1 && oky0) v10 = confi[(((size_t)b * HH + yi)     * WW + xi + 1) * OC + k];
        if (okx0 && oky1) v01 = confi[(((size_t)b * HH + yi + 1) * WW + xi)     * OC + k];
        if (okx1 && oky1) v11 = confi[(((size_t)b * HH + yi + 1) * WW + xi + 1) * OC + k];
        samp = v00 * (1.f - wx) * (1.f - wy) + v10 * wx * (1.f - wy)
             + v01 * (1.f - wx) * wy         + v11 * wx * wy;
    }
#pragma unroll
    for (int m = 16; m >= 1; m >>= 1) samp += __shfl_xor(samp, m, 64);

    if (k == 0) {
        float conf = samp * (1.0f / (float)OC);
        out[box] = 1.f / (1.f + expf(-conf));
    }
}

// ================= launch =================
extern "C" void kernel_launch(void* const* d_in, const int* in_sizes, int n_in,
                              void* d_out, int out_size, void* d_ws, size_t ws_size,
                              hipStream_t stream)
{
    const float* feat  = (const float*)d_in[0];
    const float* w1    = (const float*)d_in[1];
    const float* gamma = (const float*)d_in[2];
    const float* beta  = (const float*)d_in[3];
    const float* rmean = (const float*)d_in[4];
    const float* rvar  = (const float*)d_in[5];
    const float* w2    = (const float*)d_in[6];
    const float* boxes = (const float*)d_in[7];
    float* out = (float*)d_out;

    char* ws = (char*)d_ws;
    float*          confi = (float*)ws;                              // 63,336,448 B
    unsigned short* featp = (unsigned short*)(ws + 63336448);        // 144,769,024 B
    unsigned short* w1p   = (unsigned short*)(ws + 208105472);       // 294,912 B
    unsigned short* w2pB  = (unsigned short*)(ws + 208400384);       // 8,192 B
    float*          bnsc  = (float*)(ws + 208408576);                // 512 B
    float*          bnsh  = (float*)(ws + 208409088);                // 512 B
    unsigned short* zbuf  = (unsigned short*)(ws + 208409600);       // 256 B (ZOFF target)

    prep_kernel<<<576, 256, 0, stream>>>(w1, gamma, beta, rmean, rvar, w2,
                                         w1p, w2pB, bnsc, bnsh, zbuf);

    prepass_kernel<<<NB * 2209, 256, 0, stream>>>(feat, featp);

    dim3 grid(24, 24, NB);   // 16x16 px tiles, batch
    conv_mfma<<<grid, 256, 0, stream>>>(featp, w1p, bnsc, bnsh, w2pB, confi);

    sample_kernel<<<NB * NBOX / 8, 256, 0, stream>>>(confi, boxes, out);
}

// Round 11
// 272.436 us; speedup vs baseline: 1.2604x; 1.2604x over previous
//
#include <hip/hip_runtime.h>
#include <math.h>

#define NB   4
#define NBOX 512
#define CI   128
#define HH   376
#define WW   376
#define OC   28
#define HW   (HH * WW)   // 141376

typedef short short8  __attribute__((ext_vector_type(8)));
typedef __bf16 bf16x8 __attribute__((ext_vector_type(8)));
typedef float f32x16  __attribute__((ext_vector_type(16)));
typedef unsigned uint4v __attribute__((ext_vector_type(4)));

typedef const __attribute__((address_space(1))) void gas_void;
typedef __attribute__((address_space(3))) void las_void;

__device__ inline unsigned short f2bf(float f) {
    unsigned u = __builtin_bit_cast(unsigned, f);
    u = u + 0x7fffu + ((u >> 16) & 1u);   // RNE
    return (unsigned short)(u >> 16);
}

__device__ inline unsigned cvtpk_bf16(float lo, float hi) {
    unsigned r;
    asm("v_cvt_pk_bf16_f32 %0, %1, %2" : "=v"(r) : "v"(lo), "v"(hi));
    return r;
}

__device__ inline f32x16 mfma32(short8 a, short8 b, f32x16 c) {
    return __builtin_amdgcn_mfma_f32_32x32x16_bf16(
        __builtin_bit_cast(bf16x8, a), __builtin_bit_cast(bf16x8, b), c, 0, 0, 0);
}

// ================= prep: weights / BN / zero-slot =================
// w1p layout (TAP-MAJOR): [chunk=8][tap=9][co=128][slot s'][8 ci], s' = s ^ ((co>>2)&1)
__global__ void __launch_bounds__(256)
prep_kernel(const float* __restrict__ w1, const float* __restrict__ gamma,
            const float* __restrict__ beta, const float* __restrict__ rmean,
            const float* __restrict__ rvar, const float* __restrict__ w2,
            unsigned short* __restrict__ w1p, unsigned short* __restrict__ w2pB,
            float* __restrict__ bnsc, float* __restrict__ bnsh,
            unsigned short* __restrict__ zbuf)
{
    int idx = blockIdx.x * 256 + threadIdx.x;
    if (idx < 8 * 9 * 128 * 16) {          // 147456
        int e    = idx & 7;
        int sp   = (idx >> 3) & 1;
        int t2   = idx >> 4;               // (chunk*9 + tap)*128 + co
        int co   = t2 & 127;
        int t3   = t2 >> 7;                // chunk*9 + tap
        int tap  = t3 % 9;
        int chnk = t3 / 9;
        int s    = sp ^ ((co >> 2) & 1);
        int ci   = chnk * 16 + s * 8 + e;
        w1p[idx] = f2bf(w1[((size_t)co * CI + ci) * 9 + tap]);
    }
    if (idx < 32 * 128) {                  // w2pB [32 o][128 co]
        int o = idx >> 7, k = idx & 127;
        w2pB[idx] = (o < OC) ? f2bf(w2[o * CI + k]) : (unsigned short)0;
    }
    if (idx < CI) {
        float rs = rsqrtf(rvar[idx] + 1e-3f);
        bnsc[idx] = gamma[idx] * rs;
        bnsh[idx] = beta[idx] - rmean[idx] * gamma[idx] * rs;
    }
    if (idx < 128) zbuf[idx] = 0;
}

// ================= prepass: feat [b][ci][y][x] f32 -> featp [b][y][x][128] bf16 =================
__global__ void __launch_bounds__(256)
prepass_kernel(const float* __restrict__ feat, unsigned short* __restrict__ featp)
{
    __shared__ unsigned short xl[64 * 136];
    const int t  = threadIdx.x;
    const int bb = blockIdx.x;                 // 4 * 2209
    const int b  = bb / 2209;
    const int s0 = (bb - b * 2209) * 64;

    const int pxq = t & 15;
    const int cib = t >> 4;
#pragma unroll
    for (int it = 0; it < 8; ++it) {
        int ci = it * 16 + cib;
        float4 v = *(const float4*)(feat + ((size_t)(b * CI + ci)) * HW + s0 + pxq * 4);
#pragma unroll
        for (int j = 0; j < 4; ++j)
            xl[(pxq * 4 + j) * 136 + ci] = f2bf((&v.x)[j]);
    }
    __syncthreads();
#pragma unroll
    for (int it = 0; it < 4; ++it) {
        int n  = it * 256 + t;                 // 0..1023
        int px = n >> 4, cs = n & 15;
        short8 v = *(const short8*)(xl + px * 136 + cs * 8);
        *(short8*)(featp + ((size_t)b * HW + s0 + px) * 128 + cs * 8) = v;
    }
}

// ================= fused conv: 3x3 MFMA + BN + ReLU + 1x1 MFMA =================
// block = 256 thr (4 waves), tile 16x16 px x 128 co. Wave w: local rows [4w,4w+4).
// 32x32x16 MFMA, swapped operands: A=weights(rows=co), B=feat(cols=px) -> C[co][px].
// r3 structure with TAP-SPLIT weight staging: phase A stages featl + taps0-4
// (20.5 KB), computes them; phase B overwrites the SAME region with taps5-8
// (16.4 KB), computes them. LDS = 31,744 B -> 4 blocks/CU (vs r3's 2-3): the
// doubled block residency fills the per-chunk barrier stalls that held r3 at
// MfmaUtil 40%. Read ratio (6 b128 : 8 MFMA) unchanged from r3.
__global__ void __launch_bounds__(256, 2)
conv_mfma(const unsigned short* __restrict__ featp,
          const unsigned short* __restrict__ w1p,
          const float* __restrict__ bnsc, const float* __restrict__ bnsh,
          const unsigned short* __restrict__ w2pB,
          const unsigned short* __restrict__ zbuf,
          float* __restrict__ confi)
{
    __shared__ unsigned short sm[15872];   // featl 5632 + wl 10240 shorts = 31,744 B
    unsigned short* featl = sm;            // [352 px][16 ci] (324 real = 18x18 halo)
    unsigned short* wl    = sm + 5632;     // phase A: [5 tap][128 co][2 slot][8 ci]
                                           // phase B: [4 tap][128 co][2 slot][8 ci]

    const int tid  = threadIdx.x;
    const int w    = tid >> 6;             // 0..3
    const int lane = tid & 63;
    const int l31  = lane & 31;
    const int h    = lane >> 5;
    const int x0   = blockIdx.x * 16;
    const int y0   = blockIdx.y * 16;
    const int b    = blockIdx.z;

    // ---- staging source pointers (featl: 11 issues of 64 x 16B) ----
    const unsigned short* fsrc[3];
#pragma unroll
    for (int j = 0; j < 3; ++j) {
        int i  = w + 4 * j;
        int L  = i * 64 + lane;
        int px = L >> 1, s = L & 1;
        int r  = px / 18, cc = px - r * 18;
        int gy = y0 + r - 1, gx = x0 + cc - 1;
        bool ok = (px < 324) && ((unsigned)gy < HH) && ((unsigned)gx < WW);
        int sp = s ^ ((px >> 2) & 1);      // pre-swizzled source slot
        fsrc[j] = ok ? (featp + (((size_t)b * HW + (size_t)gy * WW + gx) * 128) + sp * 8)
                     : (zbuf + sp * 8);
    }

    // ---- per-lane read bases ----
    int pxb[2];
#pragma unroll
    for (int pf = 0; pf < 2; ++pf)
        pxb[pf] = (w * 4 + pf * 2 + (l31 >> 4)) * 18 + (l31 & 15);
    const int sw = h ^ ((l31 >> 2) & 1);
    int coff[4];                            // short-offset of co-frag within one tap slab
#pragma unroll
    for (int nf = 0; nf < 4; ++nf)
        coff[nf] = (nf * 32 + l31) * 16 + sw * 8;

    f32x16 acc[4][2];
#pragma unroll
    for (int nf = 0; nf < 4; ++nf)
#pragma unroll
        for (int pf = 0; pf < 2; ++pf)
#pragma unroll
            for (int e = 0; e < 16; ++e) acc[nf][pf][e] = 0.f;

    for (int chunk = 0; chunk < 8; ++chunk) {
        const unsigned short* wsrc = w1p + (size_t)chunk * 18432;
        __syncthreads();   // prev chunk's readers done
        // ---- phase A stage: featl (11 issues) + weight taps 0..4 (20 issues) ----
#pragma unroll
        for (int j = 0; j < 3; ++j) {
            int i = w + 4 * j;
            if (i < 11)
                __builtin_amdgcn_global_load_lds(
                    (gas_void*)(fsrc[j] + chunk * 16),
                    (las_void*)(featl + i * 512), 16, 0, 0);
        }
#pragma unroll
        for (int j = 0; j < 5; ++j) {
            int i = w + 4 * j;               // 0..19, exact
            __builtin_amdgcn_global_load_lds(
                (gas_void*)(wsrc + i * 512 + lane * 8),
                (las_void*)(wl + i * 512), 16, 0, 0);
        }
        __syncthreads();   // phase-A stages landed

        // ---- compute taps 0..4 ----
#pragma unroll
        for (int tap = 0; tap < 5; ++tap) {
            const int dy = tap / 3, dx = tap - 3 * (tap / 3);
            short8 bfv[2], afv[4];
#pragma unroll
            for (int pf = 0; pf < 2; ++pf) {
                int pxl = pxb[pf] + dy * 18 + dx;
                int sl  = h ^ ((pxl >> 2) & 1);
                bfv[pf] = *(const short8*)(featl + pxl * 16 + sl * 8);
            }
#pragma unroll
            for (int nf = 0; nf < 4; ++nf)
                afv[nf] = *(const short8*)(wl + tap * 2048 + coff[nf]);
#pragma unroll
            for (int nf = 0; nf < 4; ++nf)
#pragma unroll
                for (int pf = 0; pf < 2; ++pf)
                    acc[nf][pf] = mfma32(afv[nf], bfv[pf], acc[nf][pf]);
        }

        __syncthreads();   // all waves' tap0-4 weight reads done; safe to overwrite
        // ---- phase B stage: weight taps 5..8 (16 issues) into same region ----
#pragma unroll
        for (int j = 0; j < 4; ++j) {
            int i = w + 4 * j;               // 0..15, exact
            __builtin_amdgcn_global_load_lds(
                (gas_void*)(wsrc + 10240 + i * 512 + lane * 8),
                (las_void*)(wl + i * 512), 16, 0, 0);
        }
        __syncthreads();   // phase-B stages landed

        // ---- compute taps 5..8 (featl unchanged) ----
#pragma unroll
        for (int tap = 5; tap < 9; ++tap) {
            const int dy = tap / 3, dx = tap - 3 * (tap / 3);
            short8 bfv[2], afv[4];
#pragma unroll
            for (int pf = 0; pf < 2; ++pf) {
                int pxl = pxb[pf] + dy * 18 + dx;
                int sl  = h ^ ((pxl >> 2) & 1);
                bfv[pf] = *(const short8*)(featl + pxl * 16 + sl * 8);
            }
#pragma unroll
            for (int nf = 0; nf < 4; ++nf)
                afv[nf] = *(const short8*)(wl + (tap - 5) * 2048 + coff[nf]);
#pragma unroll
            for (int nf = 0; nf < 4; ++nf)
#pragma unroll
                for (int pf = 0; pf < 2; ++pf)
                    acc[nf][pf] = mfma32(afv[nf], bfv[pf], acc[nf][pf]);
        }
    }

    // ---- BN + ReLU (co = 32nf + (reg&3) + 8q + 4h) ----
#pragma unroll
    for (int nf = 0; nf < 4; ++nf)
#pragma unroll
        for (int q = 0; q < 4; ++q) {
            float4 s4 = *(const float4*)(bnsc + nf * 32 + q * 8 + 4 * h);
            float4 t4 = *(const float4*)(bnsh + nf * 32 + q * 8 + 4 * h);
#pragma unroll
            for (int r = 0; r < 4; ++r)
#pragma unroll
                for (int pf = 0; pf < 2; ++pf)
                    acc[nf][pf][q * 4 + r] =
                        fmaxf(acc[nf][pf][q * 4 + r] * (&s4.x)[r] + (&t4.x)[r], 0.f);
        }

    // ---- 1x1 conv fully in-register: pack acc -> bf16 A-frags (cvt_pk + half-swap) ----
#pragma unroll
    for (int pf = 0; pf < 2; ++pf) {
        f32x16 o2;
#pragma unroll
        for (int e = 0; e < 16; ++e) o2[e] = 0.f;
#pragma unroll
        for (int nf = 0; nf < 4; ++nf) {
#pragma unroll
            for (int half = 0; half < 2; ++half) {
                const int qa = half * 2, qb = half * 2 + 1;
                unsigned A0 = cvtpk_bf16(acc[nf][pf][qa * 4 + 0], acc[nf][pf][qa * 4 + 1]);
                unsigned A1 = cvtpk_bf16(acc[nf][pf][qa * 4 + 2], acc[nf][pf][qa * 4 + 3]);
                unsigned B0 = cvtpk_bf16(acc[nf][pf][qb * 4 + 0], acc[nf][pf][qb * 4 + 1]);
                unsigned B1 = cvtpk_bf16(acc[nf][pf][qb * 4 + 2], acc[nf][pf][qb * 4 + 3]);
                unsigned sA0 = (unsigned)__shfl_xor((int)A0, 32);
                unsigned sA1 = (unsigned)__shfl_xor((int)A1, 32);
                unsigned sB0 = (unsigned)__shfl_xor((int)B0, 32);
                unsigned sB1 = (unsigned)__shfl_xor((int)B1, 32);
                uint4v uv;
                uv[0] = h ? sB0 : A0;      // k = 8h+0,1
                uv[1] = h ? sB1 : A1;      // k = 8h+2,3
                uv[2] = h ? B0  : sA0;     // k = 8h+4,5
                uv[3] = h ? B1  : sA1;     // k = 8h+6,7
                short8 a2 = __builtin_bit_cast(short8, uv);
                int ks = nf * 2 + half;
                short8 wfv = *(const short8*)(w2pB + l31 * 128 + ks * 16 + h * 8);
                o2 = mfma32(a2, wfv, o2);
            }
        }
        // store: lane holds o = l31, px per-reg
#pragma unroll
        for (int reg = 0; reg < 16; ++reg) {
            int row = (reg & 3) + 8 * (reg >> 2) + 4 * h;
            int pxl = w * 64 + pf * 32 + row;
            int y = y0 + (pxl >> 4), x = x0 + (pxl & 15);
            if (l31 < OC && x < WW && y < HH)
                confi[(((size_t)b * HH + y) * WW + x) * OC + l31] = o2[reg];
        }
    }
}

// ================= rotated-grid bilinear sampling + mean + sigmoid =================
__global__ void __launch_bounds__(256)
sample_kernel(const float* __restrict__ confi, const float* __restrict__ boxes,
              float* __restrict__ out)
{
    const int tid = threadIdx.x;
    const int lb  = tid >> 5;
    const int k   = tid & 31;
    const int box = blockIdx.x * 8 + lb;
    const int b   = box >> 9;
    const int n   = box & 511;

    const float* b5 = boxes + ((size_t)b * NBOX + n) * 5;
    float xg = b5[0], yg = b5[1], wg = b5[2], lg = b5[3], rg = b5[4];
    float cr = cosf(rg), sr = sinf(rg);

    float samp = 0.f;
    if (k < OC) {
        int i = k / 7, j = k - 7 * i;
        float xx = (-0.5f + (float)i * (1.0f / 3.0f)) * wg;
        float yy = (-0.5f + (float)j * (1.0f / 6.0f)) * lg;
        float px = xx * cr + yy * sr + xg;
        float py = yy * cr - xx * sr + yg;
        float fx = px * ((float)WW / (float)(WW - 1)) - 0.5f;
        float fy = py * ((float)HH / (float)(HH - 1)) - 0.5f;
        float x0f = floorf(fx), y0f = floorf(fy);
        float wx = fx - x0f, wy = fy - y0f;
        int xi = (int)x0f, yi = (int)y0f;

        float v00 = 0.f, v10 = 0.f, v01 = 0.f, v11 = 0.f;
        bool okx0 = (xi >= 0)     && (xi <= WW - 1);
        bool okx1 = (xi + 1 >= 0) && (xi + 1 <= WW - 1);
        bool oky0 = (yi >= 0)     && (yi <= HH - 1);
        bool oky1 = (yi + 1 >= 0) && (yi + 1 <= HH - 1);
        if (okx0 && oky0) v00 = confi[(((size_t)b * HH + yi)     * WW + xi)     * OC + k];
        if (okx1 && oky0) v10 = confi[(((size_t)b * HH + yi)     * WW + xi + 1) * OC + k];
        if (okx0 && oky1) v01 = confi[(((size_t)b * HH + yi + 1) * WW + xi)     * OC + k];
        if (okx1 && oky1) v11 = confi[(((size_t)b * HH + yi + 1) * WW + xi + 1) * OC + k];
        samp = v00 * (1.f - wx) * (1.f - wy) + v10 * wx * (1.f - wy)
             + v01 * (1.f - wx) * wy         + v11 * wx * wy;
    }
#pragma unroll
    for (int m = 16; m >= 1; m >>= 1) samp += __shfl_xor(samp, m, 64);

    if (k == 0) {
        float conf = samp * (1.0f / (float)OC);
        out[box] = 1.f / (1.f + expf(-conf));
    }
}

// ================= launch =================
extern "C" void kernel_launch(void* const* d_in, const int* in_sizes, int n_in,
                              void* d_out, int out_size, void* d_ws, size_t ws_size,
                              hipStream_t stream)
{
    const float* feat  = (const float*)d_in[0];
    const float* w1    = (const float*)d_in[1];
    const float* gamma = (const float*)d_in[2];
    const float* beta  = (const float*)d_in[3];
    const float* rmean = (const float*)d_in[4];
    const float* rvar  = (const float*)d_in[5];
    const float* w2    = (const float*)d_in[6];
    const float* boxes = (const float*)d_in[7];
    float* out = (float*)d_out;

    char* ws = (char*)d_ws;
    float*          confi = (float*)ws;                              // 63,336,448 B
    unsigned short* featp = (unsigned short*)(ws + 63336448);        // 144,769,024 B
    unsigned short* w1p   = (unsigned short*)(ws + 208105472);       // 294,912 B
    unsigned short* w2pB  = (unsigned short*)(ws + 208400384);       // 8,192 B
    float*          bnsc  = (float*)(ws + 208408576);                // 512 B
    float*          bnsh  = (float*)(ws + 208409088);                // 512 B
    unsigned short* zbuf  = (unsigned short*)(ws + 208409600);       // 256 B

    prep_kernel<<<576, 256, 0, stream>>>(w1, gamma, beta, rmean, rvar, w2,
                                         w1p, w2pB, bnsc, bnsh, zbuf);

    prepass_kernel<<<NB * 2209, 256, 0, stream>>>(feat, featp);

    dim3 grid(24, 24, NB);   // 16x16 px tiles, batch
    conv_mfma<<<grid, 256, 0, stream>>>(featp, w1p, bnsc, bnsh, w2pB, zbuf, confi);

    sample_kernel<<<NB * NBOX / 8, 256, 0, stream>>>(confi, boxes, out);
}